// Round 6
// baseline (460.069 us; speedup 1.0000x reference)
//
#include <hip/hip_runtime.h>
#include <hip/hip_bf16.h>

typedef __attribute__((ext_vector_type(8)))  short short8;
typedef __attribute__((ext_vector_type(4)))  float f32x4;
typedef __attribute__((ext_vector_type(16))) float f32x16;

__device__ __forceinline__ unsigned short f2bf(float x) {
  __hip_bfloat16 h = __float2bfloat16(x);
  return (unsigned short)__builtin_bit_cast(short, h);
}
__device__ __forceinline__ unsigned packbf2(float lo, float hi2) {
  return (unsigned)f2bf(lo) | ((unsigned)f2bf(hi2) << 16);
}
__device__ __forceinline__ short8 pack8(const float* v) {
  union { unsigned u[4]; short8 s; } c;
  #pragma unroll
  for (int j = 0; j < 4; ++j) c.u[j] = packbf2(v[2 * j], v[2 * j + 1]);
  return c.s;
}

// Pack W1 (rows 0..42 = W1, row 43 = b1 [bias via X's k=43 == 1.0], 44..47 = 0)
// and W2 (256x256) into 32x32x16 bf16 A-fragment order; zero the output vec.
// Frag f: lane holds A[h = 32mt+(lane&31)][k = 16ks+8*(lane>>5)+i].
__global__ void repack_zero(const float* __restrict__ W1, const float* __restrict__ b1,
                            const float* __restrict__ W2,
                            short* __restrict__ Wp, float* __restrict__ out, int outn) {
  int id = blockIdx.x * 256 + threadIdx.x;
  if (blockIdx.x == 0 && threadIdx.x < outn) out[threadIdx.x] = 0.f;
  if (id >= 152 * 64) return;
  int fragidx = id >> 6, lane = id & 63;
  short8 v;
  if (fragidx < 24) {
    int ks = fragidx >> 3, mt = fragidx & 7;
    int h = 32 * mt + (lane & 31);
    int k0 = 16 * ks + 8 * (lane >> 5);
    #pragma unroll
    for (int i = 0; i < 8; ++i) {
      int k = k0 + i;
      float x = (k < 43) ? W1[(long)k * 256 + h] : ((k == 43) ? b1[h] : 0.f);
      v[i] = (short)f2bf(x);
    }
  } else {
    int f2 = fragidx - 24;
    int ks = f2 >> 3, mt = f2 & 7;
    int h = 32 * mt + (lane & 31);
    int k0 = 16 * ks + 8 * (lane >> 5);
    #pragma unroll
    for (int i = 0; i < 8; ++i)
      v[i] = (short)f2bf(W2[(long)(k0 + i) * 256 + h]);
  }
  *(short8*)(Wp + (long)fragidx * 512 + lane * 8) = v;
}

#define TILES 16

__launch_bounds__(512, 4)
__global__ void srm4(const float* __restrict__ obs, const float* __restrict__ act,
                     const float* __restrict__ g1, const float* __restrict__ be1,
                     const float* __restrict__ b2, const float* __restrict__ g2,
                     const float* __restrict__ be2,
                     const float* __restrict__ W3, const float* __restrict__ b3,
                     const short* __restrict__ Wp, float* __restrict__ out) {
  __shared__ float pg1[256], pe1[256];
  __shared__ float pb2[256], pg2[256], pe2[256], pw3[256];
  __shared__ float2 sq1[8][32], sq2[8][32];
  __shared__ short H1[32 * 256];   // 16 KB, XOR-swizzled

  const int tid = threadIdx.x;
  if (tid < 256) {
    pg1[tid] = g1[tid]; pe1[tid] = be1[tid];
    pb2[tid] = b2[tid]; pg2[tid] = g2[tid]; pe2[tid] = be2[tid];
    pw3[tid] = W3[tid];
  }
  const float b3v = b3[0];

  const int wave = tid >> 6, lane = tid & 63;
  const int l31 = lane & 31, hi = lane >> 5;
  const int mt = wave;                       // this wave's h-tile

  const short8* W1v = (const short8*)Wp;
  const short8* W2v = (const short8*)(Wp + 24L * 512);

  short8 w2f[16];                            // 64 VGPRs, resident all kernel
  #pragma unroll
  for (int ks = 0; ks < 16; ++ks)
    w2f[ks] = W2v[(ks * 8 + mt) * 64 + lane];

  __syncthreads();

  const int blockRow0 = blockIdx.x * (TILES * 32);
  const int bidx = blockRow0 >> 11;          // 2048 rows per batch element
  const int swz = (l31 & 15) << 4;
  float ptot = 0.f;

  #pragma unroll 1
  for (int t = 0; t < TILES; ++t) {
    const long n = blockRow0 + t * 32 + l31;
    const float* orow = obs + n * 39;
    const float* arow = act + n * 4;

    // ---- layer 1 (K padded to 48; k=43 slot = 1.0 carries b1) ----
    f32x16 acc = (f32x16)0.f;
    {
      float v[8];
      #pragma unroll
      for (int i = 0; i < 8; ++i) v[i] = orow[8 * hi + i];
      short8 bb = pack8(v);
      acc = __builtin_amdgcn_mfma_f32_32x32x16_bf16(W1v[(0 * 8 + mt) * 64 + lane], bb, acc, 0, 0, 0);
      #pragma unroll
      for (int i = 0; i < 8; ++i) v[i] = orow[16 + 8 * hi + i];
      bb = pack8(v);
      acc = __builtin_amdgcn_mfma_f32_32x32x16_bf16(W1v[(1 * 8 + mt) * 64 + lane], bb, acc, 0, 0, 0);
      #pragma unroll
      for (int i = 0; i < 8; ++i) {
        int k = 32 + 8 * hi + i;
        float tv;
        if (k < 39) tv = orow[k];
        else if (k < 43) tv = arow[k - 39];
        else tv = (k == 43) ? 1.f : 0.f;
        v[i] = tv;
      }
      bb = pack8(v);
      acc = __builtin_amdgcn_mfma_f32_32x32x16_bf16(W1v[(2 * 8 + mt) * 64 + lane], bb, acc, 0, 0, 0);
    }

    // ---- LN1 stats: lane-local over 16 h's + cross-half + cross-wave ----
    float s = 0.f, q = 0.f;
    #pragma unroll
    for (int r = 0; r < 16; ++r) { float z = acc[r]; s += z; q += z * z; }
    s += __shfl_xor(s, 32); q += __shfl_xor(q, 32);
    if (lane < 32) sq1[wave][l31] = make_float2(s, q);
    __syncthreads();                                        // B1
    s = 0.f; q = 0.f;
    #pragma unroll
    for (int j = 0; j < 8; ++j) { float2 a2 = sq1[j][l31]; s += a2.x; q += a2.y; }
    float mean = s * (1.f / 256.f);
    float rstd = rsqrtf(q * (1.f / 256.f) - mean * mean + 1e-5f);

    // ---- LN1 apply + ReLU + pack -> H1 (swizzled [32 n][256 h] bf16) ----
    #pragma unroll
    for (int qq = 0; qq < 4; ++qq) {
      const int h0 = 32 * mt + 8 * qq + 4 * hi;
      const f32x4 g4 = *(const f32x4*)&pg1[h0];
      const f32x4 e4 = *(const f32x4*)&pe1[h0];
      float val[4];
      #pragma unroll
      for (int e = 0; e < 4; ++e) {
        float a = rstd * g4[e];
        float c = fmaf(-mean, a, e4[e]);
        val[e] = fmaxf(fmaf(acc[4 * qq + e], a, c), 0.f);
      }
      unsigned lo = packbf2(val[0], val[1]);
      unsigned hw = packbf2(val[2], val[3]);
      int byteoff = (l31 * 512 + 2 * h0) ^ swz;
      *(uint2*)((char*)H1 + byteoff) = make_uint2(lo, hw);
    }
    __syncthreads();                                        // B2 (H1 ready)

    // ---- layer 2: full K=256 from LDS B-frags ----
    acc = (f32x16)0.f;
    #pragma unroll
    for (int ks = 0; ks < 16; ++ks) {
      int byteoff = (l31 * 512 + 32 * ks + 16 * hi) ^ swz;
      short8 bb = *(const short8*)((const char*)H1 + byteoff);
      acc = __builtin_amdgcn_mfma_f32_32x32x16_bf16(w2f[ks], bb, acc, 0, 0, 0);
    }

    // ---- LN2 stats (bias b2 added here) ----
    s = 0.f; q = 0.f;
    #pragma unroll
    for (int qq = 0; qq < 4; ++qq) {
      const f32x4 b4 = *(const f32x4*)&pb2[32 * mt + 8 * qq + 4 * hi];
      #pragma unroll
      for (int e = 0; e < 4; ++e) {
        float z = acc[4 * qq + e] + b4[e];
        acc[4 * qq + e] = z;
        s += z; q += z * z;
      }
    }
    s += __shfl_xor(s, 32); q += __shfl_xor(q, 32);
    if (lane < 32) sq2[wave][l31] = make_float2(s, q);
    __syncthreads();                                        // B3
    s = 0.f; q = 0.f;
    #pragma unroll
    for (int j = 0; j < 8; ++j) { float2 a2 = sq2[j][l31]; s += a2.x; q += a2.y; }
    float mean2 = s * (1.f / 256.f);
    float rstd2 = rsqrtf(q * (1.f / 256.f) - mean2 * mean2 + 1e-5f);

    // ---- LN2 apply + ReLU + W3 dot ----
    float p = 0.f;
    #pragma unroll
    for (int qq = 0; qq < 4; ++qq) {
      const int h0 = 32 * mt + 8 * qq + 4 * hi;
      const f32x4 g4 = *(const f32x4*)&pg2[h0];
      const f32x4 e4 = *(const f32x4*)&pe2[h0];
      const f32x4 w4 = *(const f32x4*)&pw3[h0];
      #pragma unroll
      for (int e = 0; e < 4; ++e) {
        float a = rstd2 * g4[e];
        float c = fmaf(-mean2, a, e4[e]);
        float val = fmaxf(fmaf(acc[4 * qq + e], a, c), 0.f);
        p = fmaf(val, w4[e], p);
      }
    }
    ptot += p;
  }

  // ---- segment sum: 8 atomics per block ----
  ptot += __shfl_xor(ptot, 32);
  #pragma unroll
  for (int off = 1; off < 32; off <<= 1) ptot += __shfl_xor(ptot, off);
  if (lane == 0) {
    float add = ptot + (wave == 0 ? (float)(TILES * 32) * b3v : 0.f);
    atomicAdd(&out[bidx], add);
  }
}

extern "C" void kernel_launch(void* const* d_in, const int* in_sizes, int n_in,
                              void* d_out, int out_size, void* d_ws, size_t ws_size,
                              hipStream_t stream) {
  const float* obs = (const float*)d_in[0];
  const float* act = (const float*)d_in[1];
  const float* W1  = (const float*)d_in[2];
  const float* b1  = (const float*)d_in[3];
  const float* g1  = (const float*)d_in[4];
  const float* be1 = (const float*)d_in[5];
  const float* W2  = (const float*)d_in[6];
  const float* b2  = (const float*)d_in[7];
  const float* g2  = (const float*)d_in[8];
  const float* be2 = (const float*)d_in[9];
  const float* W3  = (const float*)d_in[10];
  const float* b3  = (const float*)d_in[11];
  float* out = (float*)d_out;

  short* Wp = (short*)d_ws;   // 152 frags * 512 shorts = 152 KB

  repack_zero<<<38, 256, 0, stream>>>(W1, b1, W2, Wp, out, out_size);

  const int n_rows = 256 * 2048;                 // 524288
  const int n_blocks = n_rows / (TILES * 32);    // 1024
  srm4<<<n_blocks, 512, 0, stream>>>(obs, act, g1, be1,
                                     b2, g2, be2, W3, b3, Wp, out);
}

// Round 7
// 449.992 us; speedup vs baseline: 1.0224x; 1.0224x over previous
//
#include <hip/hip_runtime.h>
#include <hip/hip_bf16.h>

typedef __attribute__((ext_vector_type(8)))  short short8;
typedef __attribute__((ext_vector_type(4)))  float f32x4;
typedef __attribute__((ext_vector_type(16))) float f32x16;

__device__ __forceinline__ unsigned short f2bf(float x) {
  __hip_bfloat16 h = __float2bfloat16(x);
  return (unsigned short)__builtin_bit_cast(short, h);
}
__device__ __forceinline__ unsigned packbf2(float lo, float hi2) {
  return (unsigned)f2bf(lo) | ((unsigned)f2bf(hi2) << 16);
}
__device__ __forceinline__ short8 pack8(const float* v) {
  union { unsigned u[4]; short8 s; } c;
  #pragma unroll
  for (int j = 0; j < 4; ++j) c.u[j] = packbf2(v[2 * j], v[2 * j + 1]);
  return c.s;
}

// Pack W1 (rows 0..42 = W1, row 43 = b1 [bias via X's k=43 == 1.0], 44..47 = 0)
// and W2 (256x256) into 32x32x16 bf16 A-fragment order; zero the output vec.
// Frag f: lane holds A[h = 32mt+(lane&31)][k = 16ks+8*(lane>>5)+i].
__global__ void repack_zero(const float* __restrict__ W1, const float* __restrict__ b1,
                            const float* __restrict__ W2,
                            short* __restrict__ Wp, float* __restrict__ out, int outn) {
  int id = blockIdx.x * 256 + threadIdx.x;
  if (blockIdx.x == 0 && threadIdx.x < outn) out[threadIdx.x] = 0.f;
  if (id >= 152 * 64) return;
  int fragidx = id >> 6, lane = id & 63;
  short8 v;
  if (fragidx < 24) {
    int ks = fragidx >> 3, mt = fragidx & 7;
    int h = 32 * mt + (lane & 31);
    int k0 = 16 * ks + 8 * (lane >> 5);
    #pragma unroll
    for (int i = 0; i < 8; ++i) {
      int k = k0 + i;
      float x = (k < 43) ? W1[(long)k * 256 + h] : ((k == 43) ? b1[h] : 0.f);
      v[i] = (short)f2bf(x);
    }
  } else {
    int f2 = fragidx - 24;
    int ks = f2 >> 3, mt = f2 & 7;
    int h = 32 * mt + (lane & 31);
    int k0 = 16 * ks + 8 * (lane >> 5);
    #pragma unroll
    for (int i = 0; i < 8; ++i)
      v[i] = (short)f2bf(W2[(long)(k0 + i) * 256 + h]);
  }
  *(short8*)(Wp + (long)fragidx * 512 + lane * 8) = v;
}

#define TILES 16

__launch_bounds__(512, 4)
__global__ void srm5(const float* __restrict__ obs, const float* __restrict__ act,
                     const float* __restrict__ g1, const float* __restrict__ be1,
                     const float* __restrict__ b2, const float* __restrict__ g2,
                     const float* __restrict__ be2,
                     const float* __restrict__ W3, const float* __restrict__ b3,
                     const short* __restrict__ Wp, float* __restrict__ out) {
  __shared__ float pg1[256], pe1[256];
  __shared__ float pb2[256], pg2[256], pe2[256], pw3[256];
  __shared__ float2 sq1[8][32], sq2[8][32];
  __shared__ short H1[32 * 256];   // 16 KB, XOR-swizzled

  const int tid = threadIdx.x;
  if (tid < 256) {
    pg1[tid] = g1[tid]; pe1[tid] = be1[tid];
    pb2[tid] = b2[tid]; pg2[tid] = g2[tid]; pe2[tid] = be2[tid];
    pw3[tid] = W3[tid];
  }
  const float b3v = b3[0];

  const int wave = tid >> 6, lane = tid & 63;
  const int l31 = lane & 31, hi = lane >> 5;
  const int mt = wave;                       // this wave's 32-wide h-tile

  const short8* W1v = (const short8*)Wp;
  const short8* W2v = (const short8*)(Wp + 24L * 512);

  __syncthreads();

  const int blockRow0 = blockIdx.x * (TILES * 32);
  const int bidx = blockRow0 >> 11;          // 2048 rows per batch element
  const int swz = (l31 & 15) << 4;
  float ptot = 0.f;

  #pragma unroll 1
  for (int t = 0; t < TILES; ++t) {
    const long n = blockRow0 + t * 32 + l31;
    const float* orow = obs + n * 39;
    const float* arow = act + n * 4;

    // ---- layer 1 (K padded to 48; k=43 slot = 1.0 carries b1) ----
    f32x16 acc = (f32x16)0.f;
    {
      float v[8];
      #pragma unroll
      for (int i = 0; i < 8; ++i) v[i] = orow[8 * hi + i];
      short8 bb = pack8(v);
      acc = __builtin_amdgcn_mfma_f32_32x32x16_bf16(W1v[(0 * 8 + mt) * 64 + lane], bb, acc, 0, 0, 0);
      #pragma unroll
      for (int i = 0; i < 8; ++i) v[i] = orow[16 + 8 * hi + i];
      bb = pack8(v);
      acc = __builtin_amdgcn_mfma_f32_32x32x16_bf16(W1v[(1 * 8 + mt) * 64 + lane], bb, acc, 0, 0, 0);
      #pragma unroll
      for (int i = 0; i < 8; ++i) {
        int k = 32 + 8 * hi + i;
        float tv;
        if (k < 39) tv = orow[k];
        else if (k < 43) tv = arow[k - 39];
        else tv = (k == 43) ? 1.f : 0.f;
        v[i] = tv;
      }
      bb = pack8(v);
      acc = __builtin_amdgcn_mfma_f32_32x32x16_bf16(W1v[(2 * 8 + mt) * 64 + lane], bb, acc, 0, 0, 0);
    }

    // ---- LN1 stats: lane-local over 16 h's + cross-half + cross-wave ----
    float s = 0.f, q = 0.f;
    #pragma unroll
    for (int r = 0; r < 16; ++r) { float z = acc[r]; s += z; q += z * z; }
    s += __shfl_xor(s, 32); q += __shfl_xor(q, 32);
    if (lane < 32) sq1[wave][l31] = make_float2(s, q);
    __syncthreads();                                        // B1
    s = 0.f; q = 0.f;
    #pragma unroll
    for (int j = 0; j < 8; ++j) { float2 a2 = sq1[j][l31]; s += a2.x; q += a2.y; }
    float mean = s * (1.f / 256.f);
    float rstd = rsqrtf(q * (1.f / 256.f) - mean * mean + 1e-5f);

    // ---- issue first 4 W2 A-frag loads (consumed after B2; L2-resident) ----
    short8 wf[4];
    #pragma unroll
    for (int j = 0; j < 4; ++j) wf[j] = W2v[(j * 8 + mt) * 64 + lane];

    // ---- LN1 apply + ReLU + pack -> H1 (swizzled [32 n][256 h] bf16) ----
    #pragma unroll
    for (int qq = 0; qq < 4; ++qq) {
      const int h0 = 32 * mt + 8 * qq + 4 * hi;
      const f32x4 g4 = *(const f32x4*)&pg1[h0];
      const f32x4 e4 = *(const f32x4*)&pe1[h0];
      float val[4];
      #pragma unroll
      for (int e = 0; e < 4; ++e) {
        float a = rstd * g4[e];
        float c = fmaf(-mean, a, e4[e]);
        val[e] = fmaxf(fmaf(acc[4 * qq + e], a, c), 0.f);
      }
      unsigned lo = packbf2(val[0], val[1]);
      unsigned hw = packbf2(val[2], val[3]);
      int byteoff = (l31 * 512 + 2 * h0) ^ swz;
      *(uint2*)((char*)H1 + byteoff) = make_uint2(lo, hw);
    }
    __syncthreads();                                        // B2 (H1 ready)

    // ---- layer 2: K=256, B-frags from LDS, A-frags streamed from L2 ----
    acc = (f32x16)0.f;
    #pragma unroll
    for (int g = 0; g < 4; ++g) {
      #pragma unroll
      for (int j = 0; j < 4; ++j) {
        const int ks = 4 * g + j;
        int byteoff = (l31 * 512 + 32 * ks + 16 * hi) ^ swz;
        short8 bb = *(const short8*)((const char*)H1 + byteoff);
        acc = __builtin_amdgcn_mfma_f32_32x32x16_bf16(wf[j], bb, acc, 0, 0, 0);
        if (ks + 4 < 16) wf[j] = W2v[((ks + 4) * 8 + mt) * 64 + lane];
      }
    }

    // ---- LN2 stats (bias b2 added here) ----
    s = 0.f; q = 0.f;
    #pragma unroll
    for (int qq = 0; qq < 4; ++qq) {
      const f32x4 b4 = *(const f32x4*)&pb2[32 * mt + 8 * qq + 4 * hi];
      #pragma unroll
      for (int e = 0; e < 4; ++e) {
        float z = acc[4 * qq + e] + b4[e];
        acc[4 * qq + e] = z;
        s += z; q += z * z;
      }
    }
    s += __shfl_xor(s, 32); q += __shfl_xor(q, 32);
    if (lane < 32) sq2[wave][l31] = make_float2(s, q);
    __syncthreads();                                        // B3
    s = 0.f; q = 0.f;
    #pragma unroll
    for (int j = 0; j < 8; ++j) { float2 a2 = sq2[j][l31]; s += a2.x; q += a2.y; }
    float mean2 = s * (1.f / 256.f);
    float rstd2 = rsqrtf(q * (1.f / 256.f) - mean2 * mean2 + 1e-5f);

    // ---- LN2 apply + ReLU + W3 dot ----
    float p = 0.f;
    #pragma unroll
    for (int qq = 0; qq < 4; ++qq) {
      const int h0 = 32 * mt + 8 * qq + 4 * hi;
      const f32x4 g4 = *(const f32x4*)&pg2[h0];
      const f32x4 e4 = *(const f32x4*)&pe2[h0];
      const f32x4 w4 = *(const f32x4*)&pw3[h0];
      #pragma unroll
      for (int e = 0; e < 4; ++e) {
        float a = rstd2 * g4[e];
        float c = fmaf(-mean2, a, e4[e]);
        float val = fmaxf(fmaf(acc[4 * qq + e], a, c), 0.f);
        p = fmaf(val, w4[e], p);
      }
    }
    ptot += p;
  }

  // ---- segment sum: 8 atomics per block ----
  ptot += __shfl_xor(ptot, 32);
  #pragma unroll
  for (int off = 1; off < 32; off <<= 1) ptot += __shfl_xor(ptot, off);
  if (lane == 0) {
    float add = ptot + (wave == 0 ? (float)(TILES * 32) * b3v : 0.f);
    atomicAdd(&out[bidx], add);
  }
}

extern "C" void kernel_launch(void* const* d_in, const int* in_sizes, int n_in,
                              void* d_out, int out_size, void* d_ws, size_t ws_size,
                              hipStream_t stream) {
  const float* obs = (const float*)d_in[0];
  const float* act = (const float*)d_in[1];
  const float* W1  = (const float*)d_in[2];
  const float* b1  = (const float*)d_in[3];
  const float* g1  = (const float*)d_in[4];
  const float* be1 = (const float*)d_in[5];
  const float* W2  = (const float*)d_in[6];
  const float* b2  = (const float*)d_in[7];
  const float* g2  = (const float*)d_in[8];
  const float* be2 = (const float*)d_in[9];
  const float* W3  = (const float*)d_in[10];
  const float* b3  = (const float*)d_in[11];
  float* out = (float*)d_out;

  short* Wp = (short*)d_ws;   // 152 frags * 512 shorts = 152 KB

  repack_zero<<<38, 256, 0, stream>>>(W1, b1, W2, Wp, out, out_size);

  const int n_rows = 256 * 2048;                 // 524288
  const int n_blocks = n_rows / (TILES * 32);    // 1024
  srm5<<<n_blocks, 512, 0, stream>>>(obs, act, g1, be1,
                                     b2, g2, be2, W3, b3, Wp, out);
}